// Round 8
// baseline (883.148 us; speedup 1.0000x reference)
//
#include <hip/hip_runtime.h>
#include <math.h>

// Problem constants
#define NB 8
#define NT 512           // N_FRAMES
#define NROWS 4096       // NB*NT
#define CI 512           // C_INT
#define DM 1536          // D_MLP
#define CCON 192
#define CSPK 256
#define NW 1024          // N_WINDOW
#define FS 960           // FRAME_SIZE
#define LTOT 491520      // NT*FS
#define CONVW 1984       // FS+NW

typedef __bf16 bf16x8 __attribute__((ext_vector_type(8)));
typedef float f32x4 __attribute__((ext_vector_type(4)));
typedef unsigned short ushort;
typedef unsigned int uint;

__device__ __forceinline__ ushort f2bf(float x) {
    union { float f; unsigned u; } v; v.f = x;
    unsigned r = v.u + 0x7fff + ((v.u >> 16) & 1);
    return (ushort)(r >> 16);
}

// ---------------- weight fp32 -> bf16 (elementwise, 4/thread)
__global__ void cvt_bf16(const float* __restrict__ in, ushort* __restrict__ out, int n4) {
    int i = blockIdx.x * 256 + threadIdx.x;
    if (i < n4) {
        float4 v = ((const float4*)in)[i];
        ushort4 o; o.x = f2bf(v.x); o.y = f2bf(v.y); o.z = f2bf(v.z); o.w = f2bf(v.w);
        ((ushort4*)out)[i] = o;
    }
}

// ---------------- w_out (NW, CI, 7) -> wk[k][n][c] bf16
__global__ void cvt_wout(const float* __restrict__ w, ushort* __restrict__ wk) {
    int n = blockIdx.x, tid = threadIdx.x;
    __shared__ ushort s[7][512];
#pragma unroll
    for (int h = 0; h < 2; ++h) {
        int c = tid + h * 256;
        const float* p = w + ((size_t)n * 512 + c) * 7;
#pragma unroll
        for (int k = 0; k < 7; ++k) s[k][c] = f2bf(p[k]);
    }
    __syncthreads();
#pragma unroll
    for (int k = 0; k < 7; ++k)
#pragma unroll
        for (int h = 0; h < 2; ++h) {
            int c = tid + h * 256;
            wk[((size_t)k * NW + n) * CI + c] = s[k][c];
        }
}

// ---------------- spk base
__global__ void spkbase_kernel(const float* __restrict__ spk, const float* __restrict__ w_spk,
                               const float* __restrict__ b_spk, const float* __restrict__ b_content,
                               const float* __restrict__ b_f0, const float* __restrict__ b_energy,
                               float* __restrict__ base) {
    int b = blockIdx.x, tid = threadIdx.x;
    __shared__ float s[CSPK];
    if (tid < CSPK) s[tid] = spk[b * CSPK + tid];
    __syncthreads();
    for (int o = tid; o < CI; o += 256) {
        float acc = 0.f;
        for (int c = 0; c < CSPK; ++c) acc = fmaf(w_spk[o * CSPK + c], s[c], acc);
        base[b * CI + o] = acc + b_spk[o] + b_content[o] + b_f0[o] + b_energy[o];
    }
}

// ---------------- content transpose: (B, 192, T) -> ct[(b*T+t)][c] (bf16)
__global__ void transpose_content(const float* __restrict__ content, ushort* __restrict__ ct) {
    __shared__ float tile[32][33];
    int b = blockIdx.z, c0 = blockIdx.y * 32, t0 = blockIdx.x * 32;
    int x = threadIdx.x, y = threadIdx.y;
#pragma unroll
    for (int i = 0; i < 32; i += 8)
        tile[y + i][x] = content[((size_t)b * CCON + c0 + y + i) * NT + t0 + x];
    __syncthreads();
#pragma unroll
    for (int i = 0; i < 32; i += 8)
        ct[((size_t)b * NT + t0 + y + i) * CCON + c0 + x] = f2bf(tile[x][y + i]);
}

// ---------------- register-direct bf16 MFMA GEMM: NO LDS, NO BARRIERS.
// Block tile 64x128, 4 waves @ 32x64 (2x2). Each lane loads its MFMA fragments
// straight from global (16B contiguous per lane); compiler pipelines via vmcnt.
// MODE 0: trunk epilogue, fp32 out. MODE 1: +bias,gelu, bf16 out. MODE 2: +bias+res, fp32 out.
template <int MODE>
__global__ __launch_bounds__(256) void gemm_reg(
    const ushort* __restrict__ A, const ushort* __restrict__ W,
    const float* __restrict__ bias, void* __restrict__ outp,
    const float* __restrict__ res, int K, int NC,
    const float* __restrict__ f0, const float* __restrict__ energy,
    const float* __restrict__ w_f0, const float* __restrict__ w_energy,
    const float* __restrict__ base) {
    int tid = threadIdx.x;
    int wave = tid >> 6, lane = tid & 63;
    int lm = lane & 15, kq = lane >> 4;
    int wm = wave & 1, wn = wave >> 1;
    int m0 = blockIdx.x * 64, n0 = blockIdx.y * 128;
    const ushort* Ap = A + (size_t)(m0 + wm * 32 + lm) * K + kq * 8;
    const ushort* Wp = W + (size_t)(n0 + wn * 64 + lm) * K + kq * 8;
    f32x4 acc[2][4];
#pragma unroll
    for (int i = 0; i < 2; ++i)
#pragma unroll
        for (int j = 0; j < 4; ++j) acc[i][j] = (f32x4)0.f;

#pragma unroll 2
    for (int k0 = 0; k0 < K; k0 += 32) {
        bf16x8 af[2], bf[4];
#pragma unroll
        for (int i = 0; i < 2; ++i)
            af[i] = *(const bf16x8*)(Ap + (size_t)i * 16 * K + k0);
#pragma unroll
        for (int j = 0; j < 4; ++j)
            bf[j] = *(const bf16x8*)(Wp + (size_t)j * 16 * K + k0);
#pragma unroll
        for (int i = 0; i < 2; ++i)
#pragma unroll
            for (int j = 0; j < 4; ++j)
                acc[i][j] = __builtin_amdgcn_mfma_f32_16x16x32_bf16(af[i], bf[j], acc[i][j], 0, 0, 0);
    }

    int colv[4];
#pragma unroll
    for (int j = 0; j < 4; ++j) colv[j] = n0 + wn * 64 + j * 16 + lm;
    float p0[4], p1[4], p2[4];
#pragma unroll
    for (int j = 0; j < 4; ++j) {
        if (MODE == 0) {
            int bb = m0 >> 9;
            p0[j] = base[(bb << 9) + colv[j]];
            p1[j] = w_f0[colv[j]];
            p2[j] = w_energy[colv[j]];
        } else {
            p0[j] = bias[colv[j]];
        }
    }
#pragma unroll
    for (int i = 0; i < 2; ++i)
#pragma unroll
        for (int r = 0; r < 4; ++r) {
            int row = m0 + wm * 32 + i * 16 + kq * 4 + r;
            float fv = 0.f, ev = 0.f;
            if (MODE == 0) {
                fv = logf(fmaxf(f0[row], 0.f) + 1e-6f);
                ev = energy[row];
            }
#pragma unroll
            for (int j = 0; j < 4; ++j) {
                float v = acc[i][j][r];
                if (MODE == 0) {
                    v += p0[j] + p1[j] * fv + p2[j] * ev;
                    ((float*)outp)[(size_t)row * NC + colv[j]] = v;
                } else if (MODE == 1) {
                    v += p0[j];
                    v = 0.5f * v * (1.f + erff(v * 0.70710678118654752f));
                    ((ushort*)outp)[(size_t)row * NC + colv[j]] = f2bf(v);
                } else {
                    v += p0[j] + res[(size_t)row * NC + colv[j]];
                    ((float*)outp)[(size_t)row * NC + colv[j]] = v;
                }
            }
        }
}

// ---------------- head, register-direct: filt[m][n] = sum_{k,c} h[b,clamp(t+k-3)][c]*wk[k][n][c] + b_out[n]
// Per-lane row clamp is free (no wave-uniform LDS constraint). bf16 out.
__global__ __launch_bounds__(256) void head_reg(
    const ushort* __restrict__ H, const ushort* __restrict__ WK,
    const float* __restrict__ bias, ushort* __restrict__ out) {
    int tid = threadIdx.x;
    int wave = tid >> 6, lane = tid & 63;
    int lm = lane & 15, kq = lane >> 4;
    int wm = wave & 1, wn = wave >> 1;
    int m0 = blockIdx.x * 64, n0 = blockIdx.y * 128;
    int b = m0 >> 9, tbase = m0 & (NT - 1);
    f32x4 acc[2][4];
#pragma unroll
    for (int i = 0; i < 2; ++i)
#pragma unroll
        for (int j = 0; j < 4; ++j) acc[i][j] = (f32x4)0.f;

    for (int k = 0; k < 7; ++k) {
        const ushort* ap[2];
#pragma unroll
        for (int i = 0; i < 2; ++i) {
            int t = tbase + wm * 32 + i * 16 + lm + k - 3;
            t = min(max(t, 0), NT - 1);
            ap[i] = H + ((size_t)(b << 9) + t) * CI + kq * 8;
        }
        const ushort* wp = WK + ((size_t)k * NW + n0 + wn * 64 + lm) * CI + kq * 8;
#pragma unroll 2
        for (int c0 = 0; c0 < CI; c0 += 32) {
            bf16x8 af[2], bf[4];
#pragma unroll
            for (int i = 0; i < 2; ++i)
                af[i] = *(const bf16x8*)(ap[i] + c0);
#pragma unroll
            for (int j = 0; j < 4; ++j)
                bf[j] = *(const bf16x8*)(wp + (size_t)j * 16 * CI + c0);
#pragma unroll
            for (int i = 0; i < 2; ++i)
#pragma unroll
                for (int j = 0; j < 4; ++j)
                    acc[i][j] = __builtin_amdgcn_mfma_f32_16x16x32_bf16(af[i], bf[j], acc[i][j], 0, 0, 0);
        }
    }
#pragma unroll
    for (int i = 0; i < 2; ++i)
#pragma unroll
        for (int j = 0; j < 4; ++j) {
            int col = n0 + wn * 64 + j * 16 + lm;
            float bv = bias[col];
#pragma unroll
            for (int r = 0; r < 4; ++r) {
                int row = m0 + wm * 32 + i * 16 + kq * 4 + r;
                out[(size_t)row * NW + col] = f2bf(acc[i][j][r] + bv);
            }
        }
}

// ---------------- dw conv + LN (wave-per-row, channels strided by 64)
template <bool DW>
__global__ __launch_bounds__(256) void dwln_kernel(const float* __restrict__ X, ushort* __restrict__ H,
                                                   const float* __restrict__ dw_w,
                                                   const float* __restrict__ dw_b,
                                                   const float* __restrict__ g,
                                                   const float* __restrict__ bb) {
    __shared__ float wt[7][512];
    int tid = threadIdx.x;
    if (DW) {
        for (int i = tid; i < 3584; i += 256) {
            int c = i / 7, k = i - c * 7;
            wt[k][c] = dw_w[i];
        }
        __syncthreads();
    }
    int wid = tid >> 6, lane = tid & 63;
    int n = blockIdx.x * 4 + wid;
    int b = n >> 9, t = n & (NT - 1);
    float v[8];
    if (DW) {
#pragma unroll
        for (int i = 0; i < 8; ++i) v[i] = dw_b[lane + 64 * i];
#pragma unroll
        for (int k = 0; k < 7; ++k) {
            int tt = t + k - 3;
            if (tt >= 0 && tt < NT) {
                const float* xr = X + ((size_t)(b << 9) + tt) * CI + lane;
#pragma unroll
                for (int i = 0; i < 8; ++i)
                    v[i] = fmaf(wt[k][lane + 64 * i], xr[64 * i], v[i]);
            }
        }
    } else {
        const float* xr = X + (size_t)n * CI + lane;
#pragma unroll
        for (int i = 0; i < 8; ++i) v[i] = xr[64 * i];
    }
    float s1 = 0.f, s2 = 0.f;
#pragma unroll
    for (int i = 0; i < 8; ++i) { s1 += v[i]; s2 = fmaf(v[i], v[i], s2); }
#pragma unroll
    for (int off = 1; off < 64; off <<= 1) {
        s1 += __shfl_xor(s1, off);
        s2 += __shfl_xor(s2, off);
    }
    float mean = s1 * (1.f / CI);
    float rs = rsqrtf(s2 * (1.f / CI) - mean * mean + 1e-6f);
    ushort* hr = H + (size_t)n * CI + lane;
#pragma unroll
    for (int i = 0; i < 8; ++i) {
        int c = lane + 64 * i;
        hr[64 * i] = f2bf((v[i] - mean) * rs * g[c] + bb[c]);
    }
}

// ---------------- FIR as Toeplitz MFMA GEMM (one block per frame)
// Bcm row stride 1064 el (532 words, !=0 mod 32: frag reads are free 2-way).
__global__ __launch_bounds__(256) void fir_mfma(const float* __restrict__ source,
                                                const ushort* __restrict__ filt,
                                                float* __restrict__ conv) {
    __shared__ ushort sp[3088];          // Toeplitz src: s at el [1040,2000), zeros elsewhere
    __shared__ uint Bcm32[16 * 532];     // Bcm[ul][k]: row stride 532 dwords (1064 el)
    uint* sp32 = (uint*)sp;
    uint* G = sp32 + 1004;               // 536-dword guarded filter staging (dies before compute)
    int tid = threadIdx.x;
    int bg = blockIdx.x;
    int b = bg >> 9, g = bg & (NT - 1);

    for (int i = tid; i < 520; i += 256) sp32[i] = 0;                    // sp el [0,1040)
    if (tid < 16) G[tid] = 0;
    else if (tid < 24) G[512 + tid] = 0;                                 // G[528..535]
    const uint* fr32 = (const uint*)(filt + (size_t)bg * NW);            // 512 dwords
    G[16 + tid] = fr32[tid];
    G[272 + tid] = fr32[256 + tid];
    if (tid < 240) {
        float4 sv = ((const float4*)(source + (size_t)b * LTOT + g * FS))[tid];
        ushort4 o; o.x = f2bf(sv.x); o.y = f2bf(sv.y); o.z = f2bf(sv.z); o.w = f2bf(sv.w);
        *(ushort4*)&sp[1040 + tid * 4] = o;
    }
    __syncthreads();

    // build 16 shifted filter rows from dword window
#pragma unroll 1
    for (int p = 0; p < 3; ++p) {
        int d = tid + p * 256;
        if (d < 528) {
            uint w[9];
#pragma unroll
            for (int q = 0; q < 9; ++q) w[q] = G[d + q];
#pragma unroll
            for (int ul = 0; ul < 16; ++ul) {
                uint val;
                if ((ul & 1) == 0) val = w[8 - (ul >> 1)];
                else {
                    int a = 8 - ((ul + 1) >> 1);
                    val = (w[a] >> 16) | (w[a + 1] << 16);
                }
                Bcm32[ul * 532 + d] = val;
            }
        }
    }
    __syncthreads();

    for (int i = 1000 + tid; i < 1544; i += 256) sp32[i] = 0;   // zero sp tail (G dead)
    __syncthreads();

    int wave = tid >> 6, lane = tid & 63;
    int ln = lane & 15, kq = lane >> 4;
    const ushort* Abase = &sp[16 * ln + 8 * kq];
    const ushort* Bbase = (const ushort*)&Bcm32[ln * 532] + 8 * kq;
    int mt0 = wave * 2;
    f32x4 acc0 = (f32x4)0.f, acc1 = (f32x4)0.f;
#pragma unroll 3
    for (int kt = 0; kt < 33; ++kt) {
        bf16x8 bfrag = *(const bf16x8*)(Bbase + 32 * kt);
        bf16x8 a0 = *(const bf16x8*)(Abase + 256 * mt0 + 32 * kt);
        bf16x8 a1 = *(const bf16x8*)(Abase + 256 * (mt0 + 1) + 32 * kt);
        acc0 = __builtin_amdgcn_mfma_f32_16x16x32_bf16(a0, bfrag, acc0, 0, 0, 0);
        acc1 = __builtin_amdgcn_mfma_f32_16x16x32_bf16(a1, bfrag, acc1, 0, 0, 0);
    }
    float* cv = conv + (size_t)bg * CONVW;
#pragma unroll
    for (int r = 0; r < 4; ++r) {
        int m0 = mt0 * 16 + kq * 4 + r;
        cv[16 * m0 + ln] = acc0[r];
        int m1 = m0 + 16;
        if (m1 < 124) cv[16 * m1 + ln] = acc1[r];
    }
}

// ---------------- overlap-add fold
__global__ void fold_kernel(const float* __restrict__ conv, float* __restrict__ out) {
    int b = blockIdx.y;
    int t = blockIdx.x * blockDim.x + threadIdx.x;
    float sum = 0.f;
    int G = (t - 1) / 960;
#pragma unroll
    for (int r = 0; r < 3; ++r) {
        int g = G - r;
        if (g >= 0) {
            int u = t - 960 * g;
            if (u < CONVW) sum += conv[((size_t)(b * NT + g)) * CONVW + u];
        }
    }
    out[(size_t)b * LTOT + t] = sum;
}

extern "C" void kernel_launch(void* const* d_in, const int* in_sizes, int n_in,
                              void* d_out, int out_size, void* d_ws, size_t ws_size,
                              hipStream_t stream) {
    const float* content  = (const float*)d_in[0];
    const float* f0       = (const float*)d_in[1];
    const float* energy   = (const float*)d_in[2];
    const float* spk      = (const float*)d_in[3];
    const float* source   = (const float*)d_in[4];
    const float* w_content= (const float*)d_in[5];
    const float* b_content= (const float*)d_in[6];
    const float* w_spk    = (const float*)d_in[7];
    const float* b_spk    = (const float*)d_in[8];
    const float* w_f0     = (const float*)d_in[9];
    const float* b_f0     = (const float*)d_in[10];
    const float* w_energy = (const float*)d_in[11];
    const float* b_energy = (const float*)d_in[12];
    const float* dw_w     = (const float*)d_in[13];
    const float* dw_b     = (const float*)d_in[14];
    const float* ln_g     = (const float*)d_in[15];
    const float* ln_b     = (const float*)d_in[16];
    const float* pw1_w    = (const float*)d_in[17];
    const float* pw1_b    = (const float*)d_in[18];
    const float* pw2_w    = (const float*)d_in[19];
    const float* pw2_b    = (const float*)d_in[20];
    const float* out_ln_g = (const float*)d_in[21];
    const float* out_ln_b = (const float*)d_in[22];
    const float* w_out    = (const float*)d_in[23];
    const float* b_out    = (const float*)d_in[24];
    float* out = (float*)d_out;

    float* ws = (float*)d_ws;
    // layout (float offsets)
    float*  x     = ws;                              // 2,097,152 f
    float*  base  = ws + 2097152;                    // 4,096 f
    ushort* ctb   = (ushort*)(ws + 2101248);         // 786,432 bf16
    ushort* wcb   = (ushort*)(ws + 2494464);         // 98,304 bf16
    ushort* filtb = (ushort*)(ws + 2543616);         // 4,194,304 bf16
    ushort* h     = (ushort*)(ws + 4640768);         // 2,097,152 bf16
    ushort* pw1w  = (ushort*)(ws + 5689344);         // 4,718,592 bf16
    ushort* pw2w  = (ushort*)(ws + 8048640);         // 4,718,592 bf16
    ushort* wk    = (ushort*)(ws + 10407936);        // 3,670,016 bf16
    ushort* hmid  = (ushort*)(ws + 12242944);        // 6,291,456 bf16
    float*  conv  = ws + 5689344;                    // 8,126,464 f — overlays pw/wk/hmid (dead by fir)

    cvt_bf16<<<4608, 256, 0, stream>>>(pw1_w, pw1w, 1179648);
    cvt_bf16<<<4608, 256, 0, stream>>>(pw2_w, pw2w, 1179648);
    cvt_bf16<<<96, 256, 0, stream>>>(w_content, wcb, 24576);
    cvt_wout<<<NW, 256, 0, stream>>>(w_out, wk);
    spkbase_kernel<<<NB, 256, 0, stream>>>(spk, w_spk, b_spk, b_content, b_f0, b_energy, base);
    transpose_content<<<dim3(16, 6, NB), dim3(32, 8), 0, stream>>>(content, ctb);

    // trunk (register-direct MFMA, MODE 0)
    gemm_reg<0><<<dim3(NROWS / 64, CI / 128), 256, 0, stream>>>(
        ctb, wcb, nullptr, x, nullptr, CCON, CI, f0, energy, w_f0, w_energy, base);

    for (int i = 0; i < 6; ++i) {
        dwln_kernel<true><<<NROWS / 4, 256, 0, stream>>>(x, h, dw_w + i * CI * 7, dw_b + i * CI,
                                                         ln_g + i * CI, ln_b + i * CI);
        gemm_reg<1><<<dim3(NROWS / 64, DM / 128), 256, 0, stream>>>(
            h, pw1w + (size_t)i * DM * CI, pw1_b + i * DM, hmid, nullptr, CI, DM,
            nullptr, nullptr, nullptr, nullptr, nullptr);
        gemm_reg<2><<<dim3(NROWS / 64, CI / 128), 256, 0, stream>>>(
            hmid, pw2w + (size_t)i * CI * DM, pw2_b + i * CI, x, x, DM, CI,
            nullptr, nullptr, nullptr, nullptr, nullptr);
    }

    dwln_kernel<false><<<NROWS / 4, 256, 0, stream>>>(x, h, nullptr, nullptr, out_ln_g, out_ln_b);
    head_reg<<<dim3(NROWS / 64, NW / 128), 256, 0, stream>>>(h, wk, b_out, filtb);
    fir_mfma<<<NROWS, 256, 0, stream>>>(source, filtb, conv);
    fold_kernel<<<dim3(LTOT / 256, NB), 256, 0, stream>>>(conv, out);
}

// Round 9
// 534.081 us; speedup vs baseline: 1.6536x; 1.6536x over previous
//
#include <hip/hip_runtime.h>
#include <math.h>

// Problem constants
#define NB 8
#define NT 512           // N_FRAMES
#define NROWS 4096       // NB*NT
#define CI 512           // C_INT
#define DM 1536          // D_MLP
#define CCON 192
#define CSPK 256
#define NW 1024          // N_WINDOW
#define FS 960           // FRAME_SIZE
#define LTOT 491520      // NT*FS
#define CONVW 1984       // FS+NW

typedef __bf16 bf16x8 __attribute__((ext_vector_type(8)));
typedef float f32x4 __attribute__((ext_vector_type(4)));
typedef unsigned short ushort;
typedef unsigned int uint;

__device__ __forceinline__ ushort f2bf(float x) {
    union { float f; unsigned u; } v; v.f = x;
    unsigned r = v.u + 0x7fff + ((v.u >> 16) & 1);
    return (ushort)(r >> 16);
}

#define ASYNC_COPY16(g, l) __builtin_amdgcn_global_load_lds( \
    (const __attribute__((address_space(1))) void*)(g), \
    (__attribute__((address_space(3))) void*)(l), 16, 0, 0)

// ---------------- weight fp32 -> bf16 (elementwise, 4/thread)
__global__ void cvt_bf16(const float* __restrict__ in, ushort* __restrict__ out, int n4) {
    int i = blockIdx.x * 256 + threadIdx.x;
    if (i < n4) {
        float4 v = ((const float4*)in)[i];
        ushort4 o; o.x = f2bf(v.x); o.y = f2bf(v.y); o.z = f2bf(v.z); o.w = f2bf(v.w);
        ((ushort4*)out)[i] = o;
    }
}

// ---------------- w_out (NW, CI, 7) -> wk[k][n][c] bf16
__global__ void cvt_wout(const float* __restrict__ w, ushort* __restrict__ wk) {
    int n = blockIdx.x, tid = threadIdx.x;
    __shared__ ushort s[7][512];
#pragma unroll
    for (int h = 0; h < 2; ++h) {
        int c = tid + h * 256;
        const float* p = w + ((size_t)n * 512 + c) * 7;
#pragma unroll
        for (int k = 0; k < 7; ++k) s[k][c] = f2bf(p[k]);
    }
    __syncthreads();
#pragma unroll
    for (int k = 0; k < 7; ++k)
#pragma unroll
        for (int h = 0; h < 2; ++h) {
            int c = tid + h * 256;
            wk[((size_t)k * NW + n) * CI + c] = s[k][c];
        }
}

// ---------------- spk base
__global__ void spkbase_kernel(const float* __restrict__ spk, const float* __restrict__ w_spk,
                               const float* __restrict__ b_spk, const float* __restrict__ b_content,
                               const float* __restrict__ b_f0, const float* __restrict__ b_energy,
                               float* __restrict__ base) {
    int b = blockIdx.x, tid = threadIdx.x;
    __shared__ float s[CSPK];
    if (tid < CSPK) s[tid] = spk[b * CSPK + tid];
    __syncthreads();
    for (int o = tid; o < CI; o += 256) {
        float acc = 0.f;
        for (int c = 0; c < CSPK; ++c) acc = fmaf(w_spk[o * CSPK + c], s[c], acc);
        base[b * CI + o] = acc + b_spk[o] + b_content[o] + b_f0[o] + b_energy[o];
    }
}

// ---------------- content transpose: (B, 192, T) -> ct[(b*T+t)][c] (bf16)
__global__ void transpose_content(const float* __restrict__ content, ushort* __restrict__ ct) {
    __shared__ float tile[32][33];
    int b = blockIdx.z, c0 = blockIdx.y * 32, t0 = blockIdx.x * 32;
    int x = threadIdx.x, y = threadIdx.y;
#pragma unroll
    for (int i = 0; i < 32; i += 8)
        tile[y + i][x] = content[((size_t)b * CCON + c0 + y + i) * NT + t0 + x];
    __syncthreads();
#pragma unroll
    for (int i = 0; i < 32; i += 8)
        ct[((size_t)b * NT + t0 + y + i) * CCON + c0 + x] = f2bf(tile[x][y + i]);
}

// ---------------- 64x64 bf16 MFMA GEMM, BK=64 as two XOR-swizzled 32-planes:
// one barrier per 2 k-steps (halved drain events vs BK=32). Frag reads conflict-free.
// MODE 0: trunk epilogue, fp32 out. MODE 1: +bias,gelu, bf16 out. MODE 2: +bias+res, fp32 out.
template <int MODE>
__global__ __launch_bounds__(256) void gemm_mfma64(
    const ushort* __restrict__ A, const ushort* __restrict__ W,
    const float* __restrict__ bias, void* __restrict__ outp,
    const float* __restrict__ res, int K, int NC,
    const float* __restrict__ f0, const float* __restrict__ energy,
    const float* __restrict__ w_f0, const float* __restrict__ w_energy,
    const float* __restrict__ base) {
    __shared__ ushort As[2][64 * 32];
    __shared__ ushort Bs[2][64 * 32];
    int tid = threadIdx.x;
    int wave = tid >> 6, lane = tid & 63;
    int m0 = blockIdx.x * 64, n0 = blockIdx.y * 64;
    int srow = tid >> 2, schunk = tid & 3;
    int sg = schunk ^ ((srow >> 1) & 3);            // swizzled global chunk (per plane)
    const ushort* Ag = A + (size_t)(m0 + srow) * K + sg * 8;
    const ushort* Wg = W + (size_t)(n0 + srow) * K + sg * 8;
    const int ldst = srow * 32 + schunk * 8;
    int lm = lane & 15, kq = lane >> 4;
    int csw = (kq ^ ((lm >> 1) & 3)) * 8;           // swizzled LDS chunk for frag reads
    int wm = wave & 1, wn = wave >> 1;
    f32x4 acc[2][2];
#pragma unroll
    for (int i = 0; i < 2; ++i)
#pragma unroll
        for (int j = 0; j < 2; ++j) acc[i][j] = (f32x4)0.f;

    for (int k0 = 0; k0 < K; k0 += 64) {
        ASYNC_COPY16(Ag + k0, &As[0][ldst]);
        ASYNC_COPY16(Ag + k0 + 32, &As[1][ldst]);
        ASYNC_COPY16(Wg + k0, &Bs[0][ldst]);
        ASYNC_COPY16(Wg + k0 + 32, &Bs[1][ldst]);
        __syncthreads();
#pragma unroll
        for (int p = 0; p < 2; ++p) {
            bf16x8 af[2], bf[2];
#pragma unroll
            for (int i = 0; i < 2; ++i)
                af[i] = *(const bf16x8*)&As[p][(wm * 32 + i * 16 + lm) * 32 + csw];
#pragma unroll
            for (int j = 0; j < 2; ++j)
                bf[j] = *(const bf16x8*)&Bs[p][(wn * 32 + j * 16 + lm) * 32 + csw];
#pragma unroll
            for (int i = 0; i < 2; ++i)
#pragma unroll
                for (int j = 0; j < 2; ++j)
                    acc[i][j] = __builtin_amdgcn_mfma_f32_16x16x32_bf16(af[i], bf[j], acc[i][j], 0, 0, 0);
        }
        __syncthreads();
    }

    int colv[2];
#pragma unroll
    for (int j = 0; j < 2; ++j) colv[j] = n0 + wn * 32 + j * 16 + lm;
    float p0[2], p1[2], p2[2];
#pragma unroll
    for (int j = 0; j < 2; ++j) {
        if (MODE == 0) {
            int bb = m0 >> 9;
            p0[j] = base[(bb << 9) + colv[j]];
            p1[j] = w_f0[colv[j]];
            p2[j] = w_energy[colv[j]];
        } else {
            p0[j] = bias[colv[j]];
        }
    }
#pragma unroll
    for (int i = 0; i < 2; ++i)
#pragma unroll
        for (int r = 0; r < 4; ++r) {
            int row = m0 + wm * 32 + i * 16 + kq * 4 + r;
            float fv = 0.f, ev = 0.f;
            if (MODE == 0) {
                fv = logf(fmaxf(f0[row], 0.f) + 1e-6f);
                ev = energy[row];
            }
#pragma unroll
            for (int j = 0; j < 2; ++j) {
                float v = acc[i][j][r];
                if (MODE == 0) {
                    v += p0[j] + p1[j] * fv + p2[j] * ev;
                    ((float*)outp)[(size_t)row * NC + colv[j]] = v;
                } else if (MODE == 1) {
                    v += p0[j];
                    v = 0.5f * v * (1.f + erff(v * 0.70710678118654752f));
                    ((ushort*)outp)[(size_t)row * NC + colv[j]] = f2bf(v);
                } else {
                    v += p0[j] + res[(size_t)row * NC + colv[j]];
                    ((float*)outp)[(size_t)row * NC + colv[j]] = v;
                }
            }
        }
}

// ---------------- head (64x64, BK=64 two-plane): filt[m][n] = sum_{k,c} h[b,clamp(t+k-3)][c]*wk[k][n][c] + b_out[n]
__global__ __launch_bounds__(256) void head_mfma(
    const ushort* __restrict__ H, const ushort* __restrict__ WK,
    const float* __restrict__ bias, ushort* __restrict__ out) {
    __shared__ ushort As[2][64 * 32];
    __shared__ ushort Bs[2][64 * 32];
    int tid = threadIdx.x;
    int wave = tid >> 6, lane = tid & 63;
    int m0 = blockIdx.x * 64, n0 = blockIdx.y * 64;
    int b = m0 >> 9, tbase = m0 & (NT - 1);
    int srow = tid >> 2, schunk = tid & 3;
    int sg = schunk ^ ((srow >> 1) & 3);
    const int ldst = srow * 32 + schunk * 8;
    int lm = lane & 15, kq = lane >> 4;
    int csw = (kq ^ ((lm >> 1) & 3)) * 8;
    int wm = wave & 1, wn = wave >> 1;
    f32x4 acc[2][2];
#pragma unroll
    for (int i = 0; i < 2; ++i)
#pragma unroll
        for (int j = 0; j < 2; ++j) acc[i][j] = (f32x4)0.f;

    for (int k = 0; k < 7; ++k) {
        int t = tbase + srow + k - 3;
        t = min(max(t, 0), NT - 1);
        const ushort* Ag = H + ((size_t)(b << 9) + t) * CI + sg * 8;
        const ushort* Wg = WK + ((size_t)k * NW + n0 + srow) * CI + sg * 8;
#pragma unroll 1
        for (int c0 = 0; c0 < CI; c0 += 64) {
            ASYNC_COPY16(Ag + c0, &As[0][ldst]);
            ASYNC_COPY16(Ag + c0 + 32, &As[1][ldst]);
            ASYNC_COPY16(Wg + c0, &Bs[0][ldst]);
            ASYNC_COPY16(Wg + c0 + 32, &Bs[1][ldst]);
            __syncthreads();
#pragma unroll
            for (int p = 0; p < 2; ++p) {
                bf16x8 af[2], bf[2];
#pragma unroll
                for (int i = 0; i < 2; ++i)
                    af[i] = *(const bf16x8*)&As[p][(wm * 32 + i * 16 + lm) * 32 + csw];
#pragma unroll
                for (int j = 0; j < 2; ++j)
                    bf[j] = *(const bf16x8*)&Bs[p][(wn * 32 + j * 16 + lm) * 32 + csw];
#pragma unroll
                for (int i = 0; i < 2; ++i)
#pragma unroll
                    for (int j = 0; j < 2; ++j)
                        acc[i][j] = __builtin_amdgcn_mfma_f32_16x16x32_bf16(af[i], bf[j], acc[i][j], 0, 0, 0);
            }
            __syncthreads();
        }
    }
#pragma unroll
    for (int i = 0; i < 2; ++i)
#pragma unroll
        for (int j = 0; j < 2; ++j) {
            int col = n0 + wn * 32 + j * 16 + lm;
            float bv = bias[col];
#pragma unroll
            for (int r = 0; r < 4; ++r) {
                int row = m0 + wm * 32 + i * 16 + kq * 4 + r;
                out[(size_t)row * NW + col] = f2bf(acc[i][j][r] + bv);
            }
        }
}

// ---------------- dw conv + LN (wave-per-row, channels strided by 64)
template <bool DW>
__global__ __launch_bounds__(256) void dwln_kernel(const float* __restrict__ X, ushort* __restrict__ H,
                                                   const float* __restrict__ dw_w,
                                                   const float* __restrict__ dw_b,
                                                   const float* __restrict__ g,
                                                   const float* __restrict__ bb) {
    __shared__ float wt[7][512];
    int tid = threadIdx.x;
    if (DW) {
        for (int i = tid; i < 3584; i += 256) {
            int c = i / 7, k = i - c * 7;
            wt[k][c] = dw_w[i];
        }
        __syncthreads();
    }
    int wid = tid >> 6, lane = tid & 63;
    int n = blockIdx.x * 4 + wid;
    int b = n >> 9, t = n & (NT - 1);
    float v[8];
    if (DW) {
#pragma unroll
        for (int i = 0; i < 8; ++i) v[i] = dw_b[lane + 64 * i];
#pragma unroll
        for (int k = 0; k < 7; ++k) {
            int tt = t + k - 3;
            if (tt >= 0 && tt < NT) {
                const float* xr = X + ((size_t)(b << 9) + tt) * CI + lane;
#pragma unroll
                for (int i = 0; i < 8; ++i)
                    v[i] = fmaf(wt[k][lane + 64 * i], xr[64 * i], v[i]);
            }
        }
    } else {
        const float* xr = X + (size_t)n * CI + lane;
#pragma unroll
        for (int i = 0; i < 8; ++i) v[i] = xr[64 * i];
    }
    float s1 = 0.f, s2 = 0.f;
#pragma unroll
    for (int i = 0; i < 8; ++i) { s1 += v[i]; s2 = fmaf(v[i], v[i], s2); }
#pragma unroll
    for (int off = 1; off < 64; off <<= 1) {
        s1 += __shfl_xor(s1, off);
        s2 += __shfl_xor(s2, off);
    }
    float mean = s1 * (1.f / CI);
    float rs = rsqrtf(s2 * (1.f / CI) - mean * mean + 1e-6f);
    ushort* hr = H + (size_t)n * CI + lane;
#pragma unroll
    for (int i = 0; i < 8; ++i) {
        int c = lane + 64 * i;
        hr[64 * i] = f2bf((v[i] - mean) * rs * g[c] + bb[c]);
    }
}

// ---------------- FIR as Toeplitz MFMA GEMM (one block per frame)
__global__ __launch_bounds__(256) void fir_mfma(const float* __restrict__ source,
                                                const ushort* __restrict__ filt,
                                                float* __restrict__ conv) {
    __shared__ ushort sp[3088];          // Toeplitz src: s at el [1040,2000), zeros elsewhere
    __shared__ uint Bcm32[16 * 532];     // Bcm[ul][k]: row stride 532 dwords (1064 el)
    uint* sp32 = (uint*)sp;
    uint* G = sp32 + 1004;               // 536-dword guarded filter staging (dies before compute)
    int tid = threadIdx.x;
    int bg = blockIdx.x;
    int b = bg >> 9, g = bg & (NT - 1);

    for (int i = tid; i < 520; i += 256) sp32[i] = 0;                    // sp el [0,1040)
    if (tid < 16) G[tid] = 0;
    else if (tid < 24) G[512 + tid] = 0;                                 // G[528..535]
    const uint* fr32 = (const uint*)(filt + (size_t)bg * NW);            // 512 dwords
    G[16 + tid] = fr32[tid];
    G[272 + tid] = fr32[256 + tid];
    if (tid < 240) {
        float4 sv = ((const float4*)(source + (size_t)b * LTOT + g * FS))[tid];
        ushort4 o; o.x = f2bf(sv.x); o.y = f2bf(sv.y); o.z = f2bf(sv.z); o.w = f2bf(sv.w);
        *(ushort4*)&sp[1040 + tid * 4] = o;
    }
    __syncthreads();

    // build 16 shifted filter rows from dword window
#pragma unroll 1
    for (int p = 0; p < 3; ++p) {
        int d = tid + p * 256;
        if (d < 528) {
            uint w[9];
#pragma unroll
            for (int q = 0; q < 9; ++q) w[q] = G[d + q];
#pragma unroll
            for (int ul = 0; ul < 16; ++ul) {
                uint val;
                if ((ul & 1) == 0) val = w[8 - (ul >> 1)];
                else {
                    int a = 8 - ((ul + 1) >> 1);
                    val = (w[a] >> 16) | (w[a + 1] << 16);
                }
                Bcm32[ul * 532 + d] = val;
            }
        }
    }
    __syncthreads();

    for (int i = 1000 + tid; i < 1544; i += 256) sp32[i] = 0;   // zero sp tail (G dead)
    __syncthreads();

    int wave = tid >> 6, lane = tid & 63;
    int ln = lane & 15, kq = lane >> 4;
    const ushort* Abase = &sp[16 * ln + 8 * kq];
    const ushort* Bbase = (const ushort*)&Bcm32[ln * 532] + 8 * kq;
    int mt0 = wave * 2;
    f32x4 acc0 = (f32x4)0.f, acc1 = (f32x4)0.f;
#pragma unroll 3
    for (int kt = 0; kt < 33; ++kt) {
        bf16x8 bfrag = *(const bf16x8*)(Bbase + 32 * kt);
        bf16x8 a0 = *(const bf16x8*)(Abase + 256 * mt0 + 32 * kt);
        bf16x8 a1 = *(const bf16x8*)(Abase + 256 * (mt0 + 1) + 32 * kt);
        acc0 = __builtin_amdgcn_mfma_f32_16x16x32_bf16(a0, bfrag, acc0, 0, 0, 0);
        acc1 = __builtin_amdgcn_mfma_f32_16x16x32_bf16(a1, bfrag, acc1, 0, 0, 0);
    }
    float* cv = conv + (size_t)bg * CONVW;
#pragma unroll
    for (int r = 0; r < 4; ++r) {
        int m0 = mt0 * 16 + kq * 4 + r;
        cv[16 * m0 + ln] = acc0[r];
        int m1 = m0 + 16;
        if (m1 < 124) cv[16 * m1 + ln] = acc1[r];
    }
}

// ---------------- overlap-add fold
__global__ void fold_kernel(const float* __restrict__ conv, float* __restrict__ out) {
    int b = blockIdx.y;
    int t = blockIdx.x * blockDim.x + threadIdx.x;
    float sum = 0.f;
    int G = (t - 1) / 960;
#pragma unroll
    for (int r = 0; r < 3; ++r) {
        int g = G - r;
        if (g >= 0) {
            int u = t - 960 * g;
            if (u < CONVW) sum += conv[((size_t)(b * NT + g)) * CONVW + u];
        }
    }
    out[(size_t)b * LTOT + t] = sum;
}

extern "C" void kernel_launch(void* const* d_in, const int* in_sizes, int n_in,
                              void* d_out, int out_size, void* d_ws, size_t ws_size,
                              hipStream_t stream) {
    const float* content  = (const float*)d_in[0];
    const float* f0       = (const float*)d_in[1];
    const float* energy   = (const float*)d_in[2];
    const float* spk      = (const float*)d_in[3];
    const float* source   = (const float*)d_in[4];
    const float* w_content= (const float*)d_in[5];
    const float* b_content= (const float*)d_in[6];
    const float* w_spk    = (const float*)d_in[7];
    const float* b_spk    = (const float*)d_in[8];
    const float* w_f0     = (const float*)d_in[9];
    const float* b_f0     = (const float*)d_in[10];
    const float* w_energy = (const float*)d_in[11];
    const float* b_energy = (const float*)d_in[12];
    const float* dw_w     = (const float*)d_in[13];
    const float* dw_b     = (const float*)d_in[14];
    const float* ln_g     = (const float*)d_in[15];
    const float* ln_b     = (const float*)d_in[16];
    const float* pw1_w    = (const float*)d_in[17];
    const float* pw1_b    = (const float*)d_in[18];
    const float* pw2_w    = (const float*)d_in[19];
    const float* pw2_b    = (const float*)d_in[20];
    const float* out_ln_g = (const float*)d_in[21];
    const float* out_ln_b = (const float*)d_in[22];
    const float* w_out    = (const float*)d_in[23];
    const float* b_out    = (const float*)d_in[24];
    float* out = (float*)d_out;

    float* ws = (float*)d_ws;
    // layout (float offsets)
    float*  x     = ws;                              // 2,097,152 f
    float*  base  = ws + 2097152;                    // 4,096 f
    ushort* ctb   = (ushort*)(ws + 2101248);         // 786,432 bf16
    ushort* wcb   = (ushort*)(ws + 2494464);         // 98,304 bf16
    ushort* filtb = (ushort*)(ws + 2543616);         // 4,194,304 bf16
    ushort* h     = (ushort*)(ws + 4640768);         // 2,097,152 bf16
    ushort* pw1w  = (ushort*)(ws + 5689344);         // 4,718,592 bf16
    ushort* pw2w  = (ushort*)(ws + 8048640);         // 4,718,592 bf16
    ushort* wk    = (ushort*)(ws + 10407936);        // 3,670,016 bf16
    ushort* hmid  = (ushort*)(ws + 12242944);        // 6,291,456 bf16
    float*  conv  = ws + 5689344;                    // 8,126,464 f — overlays pw/wk/hmid (dead by fir)

    cvt_bf16<<<4608, 256, 0, stream>>>(pw1_w, pw1w, 1179648);
    cvt_bf16<<<4608, 256, 0, stream>>>(pw2_w, pw2w, 1179648);
    cvt_bf16<<<96, 256, 0, stream>>>(w_content, wcb, 24576);
    cvt_wout<<<NW, 256, 0, stream>>>(w_out, wk);
    spkbase_kernel<<<NB, 256, 0, stream>>>(spk, w_spk, b_spk, b_content, b_f0, b_energy, base);
    transpose_content<<<dim3(16, 6, NB), dim3(32, 8), 0, stream>>>(content, ctb);

    // trunk (bf16 MFMA, MODE 0), K=192
    gemm_mfma64<0><<<dim3(NROWS / 64, CI / 64), 256, 0, stream>>>(
        ctb, wcb, nullptr, x, nullptr, CCON, CI, f0, energy, w_f0, w_energy, base);

    for (int i = 0; i < 6; ++i) {
        dwln_kernel<true><<<NROWS / 4, 256, 0, stream>>>(x, h, dw_w + i * CI * 7, dw_b + i * CI,
                                                         ln_g + i * CI, ln_b + i * CI);
        gemm_mfma64<1><<<dim3(NROWS / 64, DM / 64), 256, 0, stream>>>(
            h, pw1w + (size_t)i * DM * CI, pw1_b + i * DM, hmid, nullptr, CI, DM,
            nullptr, nullptr, nullptr, nullptr, nullptr);
        gemm_mfma64<2><<<dim3(NROWS / 64, CI / 64), 256, 0, stream>>>(
            hmid, pw2w + (size_t)i * CI * DM, pw2_b + i * CI, x, x, DM, CI,
            nullptr, nullptr, nullptr, nullptr, nullptr);
    }

    dwln_kernel<false><<<NROWS / 4, 256, 0, stream>>>(x, h, nullptr, nullptr, out_ln_g, out_ln_b);
    head_mfma<<<dim3(NROWS / 64, NW / 64), 256, 0, stream>>>(h, wk, b_out, filtb);
    fir_mfma<<<NROWS, 256, 0, stream>>>(source, filtb, conv);
    fold_kernel<<<dim3(LTOT / 256, NB), 256, 0, stream>>>(conv, out);
}